// Round 6
// baseline (223.029 us; speedup 1.0000x reference)
//
#include <hip/hip_runtime.h>
#include <hip/hip_bf16.h>

typedef __attribute__((ext_vector_type(8))) short short8;
typedef __attribute__((ext_vector_type(4))) float floatx4;

#define NROWS 4096
#define NHALF 2048
#define DDIM  128
#define SQRT_SCALE 2.6857914f     // sqrt(1/(0.2*ln2)); dot of stored z == (sim/T)*log2(e)
#define LN2 0.69314718056f

// ws float layout: [0]=loss acc, [1]=all_num,
// rowpart [64, +8*16384), diag [131136, +16384), pos [147520, +16384), z after.
#define WS_ROWPART_OFF 64
#define WS_DIAG_OFF   131136
#define WS_POS_OFF    147520
#define WS_Z_BYTE_OFF 655616      // (147520+16384)*4, 16B aligned

__device__ inline unsigned short f2bf(float f) {
    unsigned u = __builtin_bit_cast(unsigned, f);
    u += 0x7fffu + ((u >> 16) & 1u);          // RNE
    return (unsigned short)(u >> 16);
}

// ---------------- kernel 1: normalize + scale + cast to bf16; all_num ----------------------
__global__ __launch_bounds__(256) void k_norm(const float* __restrict__ emb_i,
                                              const float* __restrict__ emb_j,
                                              const float* __restrict__ jv,
                                              float* __restrict__ wsf,
                                              unsigned short* __restrict__ z) {
    int bx = blockIdx.x, tid = threadIdx.x;
    if (bx == 2048) {                         // all_num = sum(joint_valid)
        __shared__ float sred[256];
        float s = 0.f;
        #pragma unroll
        for (int i = 0; i < 8; ++i) s += jv[tid + 256 * i];
        sred[tid] = s; __syncthreads();
        for (int off = 128; off > 0; off >>= 1) {
            if (tid < off) sred[tid] += sred[tid + off];
            __syncthreads();
        }
        if (tid == 0) wsf[1] = sred[0];
        return;
    }
    if (bx == 0 && tid == 0) wsf[0] = 0.f;    // zero loss accumulator (ws poisoned each call)

    int wave = tid >> 6, lane = tid & 63, half = lane >> 5, sl = lane & 31;
    int r = bx * 8 + wave * 2 + half;         // global row 0..16383
    int l = r >> 12, n = r & 4095;
    const float* src = (n < NHALF) ? (emb_i + ((size_t)l * NHALF + n) * DDIM)
                                   : (emb_j + ((size_t)l * NHALF + (n - NHALF)) * DDIM);
    float4 v = *(const float4*)(src + sl * 4);
    float ss = v.x * v.x + v.y * v.y + v.z * v.z + v.w * v.w;
    #pragma unroll
    for (int off = 1; off < 32; off <<= 1) ss += __shfl_xor(ss, off);  // within 32-lane half
    float inv = SQRT_SCALE / fmaxf(sqrtf(ss), 1e-12f);
    unsigned p0 = ((unsigned)f2bf(v.y * inv) << 16) | (unsigned)f2bf(v.x * inv);
    unsigned p1 = ((unsigned)f2bf(v.w * inv) << 16) | (unsigned)f2bf(v.z * inv);
    *(uint2*)(z + (size_t)r * DDIM + sl * 4) = (uint2){p0, p1};
}

// ---------------- kernel 2: LDS-free streaming sim, occupancy-first ------------------------
// grid 1024: rb(32 bands x 128 rows) | l(4) | cg(8 x 512 cols). 4 waves x 32 rows.
// __launch_bounds__(256,4): cap 128 VGPR -> 4 waves/SIMD; 4 blocks/CU; co-resident
// blocks share l+cg (same B stream -> L1 reuse). Straight-line, 2-deep B double buffer.
#define SIMSTEP(BB, CS)                                                                       \
    {                                                                                         \
        int c0 = C0 + (CS) * 16;                                                              \
        _Pragma("unroll")                                                                     \
        for (int rs = 0; rs < 2; ++rs) {                                                      \
            floatx4 acc = (floatx4){0.f, 0.f, 0.f, 0.f};                                      \
            acc = __builtin_amdgcn_mfma_f32_16x16x32_bf16(a[rs][0], BB[0], acc, 0, 0, 0);     \
            acc = __builtin_amdgcn_mfma_f32_16x16x32_bf16(a[rs][1], BB[1], acc, 0, 0, 0);     \
            acc = __builtin_amdgcn_mfma_f32_16x16x32_bf16(a[rs][2], BB[2], acc, 0, 0, 0);     \
            acc = __builtin_amdgcn_mfma_f32_16x16x32_bf16(a[rs][3], BB[3], acc, 0, 0, 0);     \
            int rbase = R0 + rs * 16;                                                         \
            if (c0 == rbase || c0 == (rbase ^ 2048)) {  /* rare, wave-uniform */              \
                int c = m - (quad << 2);                                                      \
                if (c >= 0 && c < 4)                                                          \
                    ((c0 == rbase) ? diag : pos)[l4 + rbase + m] = acc[c];                    \
            }                                                                                 \
            rsum[rs][0] += __builtin_amdgcn_exp2f(acc[0]);                                    \
            rsum[rs][1] += __builtin_amdgcn_exp2f(acc[1]);                                    \
            rsum[rs][2] += __builtin_amdgcn_exp2f(acc[2]);                                    \
            rsum[rs][3] += __builtin_amdgcn_exp2f(acc[3]);                                    \
        }                                                                                     \
    }

__global__ __launch_bounds__(256, 4) void k_sim(const unsigned short* __restrict__ z,
                                                float* __restrict__ rowpart,
                                                float* __restrict__ diag,
                                                float* __restrict__ pos) {
    int bx = blockIdx.x, tid = threadIdx.x;
    int rb = bx & 31, l = (bx >> 5) & 3, cg = bx >> 7;
    int wave = tid >> 6, lane = tid & 63, m = lane & 15, quad = lane >> 4;
    const unsigned short* zl = z + (size_t)l * NROWS * DDIM;
    int l4 = l * NROWS;
    int R0 = rb * 128 + wave * 32;            // wave's row base (local to l)
    int C0 = cg * 512;                        // block's col base

    short8 a[2][4];                           // 2 row-subtiles x 4 k-steps (32 VGPR)
    #pragma unroll
    for (int rs = 0; rs < 2; ++rs) {
        const unsigned short* p = zl + (size_t)(R0 + rs * 16 + m) * DDIM + quad * 8;
        #pragma unroll
        for (int kk = 0; kk < 4; ++kk) a[rs][kk] = *(const short8*)(p + kk * 32);
    }
    floatx4 rsum[2];
    rsum[0] = (floatx4){0.f, 0.f, 0.f, 0.f};
    rsum[1] = (floatx4){0.f, 0.f, 0.f, 0.f};

    const unsigned short* bp = zl + (size_t)(C0 + m) * DDIM + quad * 8;
    short8 b0[4], b1[4];
    #pragma unroll
    for (int k = 0; k < 4; ++k) b0[k] = *(const short8*)(bp + k * 32);

    for (int cs = 0; cs < 32; cs += 2) {      // 16-col steps, paired double-buffer
        const unsigned short* q1 = bp + (size_t)(cs + 1) * (16 * DDIM);
        #pragma unroll
        for (int k = 0; k < 4; ++k) b1[k] = *(const short8*)(q1 + k * 32);
        SIMSTEP(b0, cs)
        if (cs + 2 < 32) {
            const unsigned short* q2 = bp + (size_t)(cs + 2) * (16 * DDIM);
            #pragma unroll
            for (int k = 0; k < 4; ++k) b0[k] = *(const short8*)(q2 + k * 32);
        }
        SIMSTEP(b1, cs + 1)
    }

    // reduce across the 16 column-lanes (bits 0..3 of lane)
    #pragma unroll
    for (int off = 1; off < 16; off <<= 1)
        #pragma unroll
        for (int rs = 0; rs < 2; ++rs)
            #pragma unroll
            for (int c = 0; c < 4; ++c)
                rsum[rs][c] += __shfl_xor(rsum[rs][c], off);
    if (m == 0) {                             // plain stores: unique (cg,row) per value
        #pragma unroll
        for (int rs = 0; rs < 2; ++rs)
            #pragma unroll
            for (int c = 0; c < 4; ++c) {
                int rg = R0 + rs * 16 + quad * 4 + c;
                rowpart[cg * 16384 + l4 + rg] = rsum[rs][c];
            }
    }
}

// ---------------- kernel 3: per-row loss from rowpart/diag/pos, 1 atomic per block ---------
__global__ __launch_bounds__(256) void k_loss(const float* __restrict__ jv,
                                              const float* __restrict__ rowpart,
                                              const float* __restrict__ diag,
                                              const float* __restrict__ pos,
                                              float* __restrict__ wsf) {
    __shared__ float sred[256];
    int tid = threadIdx.x;
    int r = blockIdx.x * 256 + tid;           // 64 blocks x 256 = 16384 rows
    int n = r & 4095;
    float tot = 0.f;
    #pragma unroll
    for (int g = 0; g < 8; ++g) tot += rowpart[g * 16384 + r];
    float denom = tot - __builtin_amdgcn_exp2f(diag[r]);   // exact cancel of diagonal term
    float contrib = LN2 * (__builtin_amdgcn_logf(denom) - pos[r]);
    float local = contrib * jv[n & (NHALF - 1)];
    sred[tid] = local; __syncthreads();
    for (int off = 128; off > 0; off >>= 1) {
        if (tid < off) sred[tid] += sred[tid + off];
        __syncthreads();
    }
    if (tid == 0) atomicAdd(&wsf[0], sred[0]);
}

// ---------------- kernel 4: final scalar ---------------------------------------------------
__global__ void k_final(const float* __restrict__ wsf, float* __restrict__ out) {
    if (threadIdx.x == 0) out[0] = wsf[0] / (2.f * wsf[1]);
}

extern "C" void kernel_launch(void* const* d_in, const int* in_sizes, int n_in,
                              void* d_out, int out_size, void* d_ws, size_t ws_size,
                              hipStream_t stream) {
    const float* emb_i = (const float*)d_in[0];
    const float* emb_j = (const float*)d_in[1];
    const float* jv    = (const float*)d_in[2];
    float* wsf     = (float*)d_ws;
    float* rowpart = wsf + WS_ROWPART_OFF;
    float* diag    = wsf + WS_DIAG_OFF;
    float* pos     = wsf + WS_POS_OFF;
    unsigned short* z = (unsigned short*)((char*)d_ws + WS_Z_BYTE_OFF);
    float* out = (float*)d_out;

    k_norm <<<2049, 256, 0, stream>>>(emb_i, emb_j, jv, wsf, z);
    k_sim  <<<1024, 256, 0, stream>>>(z, rowpart, diag, pos);
    k_loss <<<64,   256, 0, stream>>>(jv, rowpart, diag, pos, wsf);
    k_final<<<1,    64,  0, stream>>>(wsf, out);
}

// Round 7
// 128.750 us; speedup vs baseline: 1.7323x; 1.7323x over previous
//
#include <hip/hip_runtime.h>
#include <hip/hip_bf16.h>

typedef __attribute__((ext_vector_type(8))) short short8;
typedef __attribute__((ext_vector_type(4))) float floatx4;

#define NROWS 4096
#define NHALF 2048
#define DDIM  128
#define SQRT_SCALE 2.6857914f     // sqrt(1/(0.2*ln2)); dot of stored z == (sim/T)*log2(e)
#define LN2 0.69314718056f

// ws float layout: [0]=loss acc, [1]=all_num,
// rowpart [64, +8*16384), diag [131136, +16384), pos [147520, +16384), z after.
#define WS_ROWPART_OFF 64
#define WS_DIAG_OFF   131136
#define WS_POS_OFF    147520
#define WS_Z_BYTE_OFF 655616      // (147520+16384)*4, 16B aligned

__device__ inline unsigned short f2bf(float f) {
    unsigned u = __builtin_bit_cast(unsigned, f);
    u += 0x7fffu + ((u >> 16) & 1u);          // RNE
    return (unsigned short)(u >> 16);
}

// ---------------- kernel 1: normalize + scale + cast to bf16; all_num ----------------------
__global__ __launch_bounds__(256) void k_norm(const float* __restrict__ emb_i,
                                              const float* __restrict__ emb_j,
                                              const float* __restrict__ jv,
                                              float* __restrict__ wsf,
                                              unsigned short* __restrict__ z) {
    int bx = blockIdx.x, tid = threadIdx.x;
    if (bx == 2048) {                         // all_num = sum(joint_valid)
        __shared__ float sred[256];
        float s = 0.f;
        #pragma unroll
        for (int i = 0; i < 8; ++i) s += jv[tid + 256 * i];
        sred[tid] = s; __syncthreads();
        for (int off = 128; off > 0; off >>= 1) {
            if (tid < off) sred[tid] += sred[tid + off];
            __syncthreads();
        }
        if (tid == 0) wsf[1] = sred[0];
        return;
    }
    if (bx == 0 && tid == 0) wsf[0] = 0.f;    // zero loss accumulator (ws poisoned each call)

    int wave = tid >> 6, lane = tid & 63, half = lane >> 5, sl = lane & 31;
    int r = bx * 8 + wave * 2 + half;         // global row 0..16383
    int l = r >> 12, n = r & 4095;
    const float* src = (n < NHALF) ? (emb_i + ((size_t)l * NHALF + n) * DDIM)
                                   : (emb_j + ((size_t)l * NHALF + (n - NHALF)) * DDIM);
    float4 v = *(const float4*)(src + sl * 4);
    float ss = v.x * v.x + v.y * v.y + v.z * v.z + v.w * v.w;
    #pragma unroll
    for (int off = 1; off < 32; off <<= 1) ss += __shfl_xor(ss, off);  // within 32-lane half
    float inv = SQRT_SCALE / fmaxf(sqrtf(ss), 1e-12f);
    unsigned p0 = ((unsigned)f2bf(v.y * inv) << 16) | (unsigned)f2bf(v.x * inv);
    unsigned p1 = ((unsigned)f2bf(v.w * inv) << 16) | (unsigned)f2bf(v.z * inv);
    *(uint2*)(z + (size_t)r * DDIM + sl * 4) = (uint2){p0, p1};
}

// ---------------- kernel 2: LDS-free streaming sim, occupancy-first ------------------------
// grid 1024: rb(32 bands x 128 rows) | l(4) | cg(8 x 512 cols). 4 waves x 32 rows.
// NO launch_bounds occupancy clamp — R6 showed (256,4) forces VGPR=64 + scratch spills
// (148 MB fetch / 260 MB write of spill traffic). Natural demand ~100-130 VGPR ->
// 3-5 waves/SIMD unclamped. Straight-line, 2-deep paired B double buffer, plain stores.
#define SIMSTEP(BB, CS)                                                                       \
    {                                                                                         \
        int c0 = C0 + (CS) * 16;                                                              \
        _Pragma("unroll")                                                                     \
        for (int rs = 0; rs < 2; ++rs) {                                                      \
            floatx4 acc = (floatx4){0.f, 0.f, 0.f, 0.f};                                      \
            acc = __builtin_amdgcn_mfma_f32_16x16x32_bf16(a[rs][0], BB[0], acc, 0, 0, 0);     \
            acc = __builtin_amdgcn_mfma_f32_16x16x32_bf16(a[rs][1], BB[1], acc, 0, 0, 0);     \
            acc = __builtin_amdgcn_mfma_f32_16x16x32_bf16(a[rs][2], BB[2], acc, 0, 0, 0);     \
            acc = __builtin_amdgcn_mfma_f32_16x16x32_bf16(a[rs][3], BB[3], acc, 0, 0, 0);     \
            int rbase = R0 + rs * 16;                                                         \
            if (c0 == rbase || c0 == (rbase ^ 2048)) {  /* rare, wave-uniform */              \
                int c = m - (quad << 2);                                                      \
                if (c >= 0 && c < 4)                                                          \
                    ((c0 == rbase) ? diag : pos)[l4 + rbase + m] = acc[c];                    \
            }                                                                                 \
            rsum[rs][0] += __builtin_amdgcn_exp2f(acc[0]);                                    \
            rsum[rs][1] += __builtin_amdgcn_exp2f(acc[1]);                                    \
            rsum[rs][2] += __builtin_amdgcn_exp2f(acc[2]);                                    \
            rsum[rs][3] += __builtin_amdgcn_exp2f(acc[3]);                                    \
        }                                                                                     \
    }

__global__ __launch_bounds__(256) void k_sim(const unsigned short* __restrict__ z,
                                             float* __restrict__ rowpart,
                                             float* __restrict__ diag,
                                             float* __restrict__ pos) {
    int bx = blockIdx.x, tid = threadIdx.x;
    int rb = bx & 31, l = (bx >> 5) & 3, cg = bx >> 7;
    int wave = tid >> 6, lane = tid & 63, m = lane & 15, quad = lane >> 4;
    const unsigned short* zl = z + (size_t)l * NROWS * DDIM;
    int l4 = l * NROWS;
    int R0 = rb * 128 + wave * 32;            // wave's row base (local to l)
    int C0 = cg * 512;                        // block's col base

    short8 a[2][4];                           // 2 row-subtiles x 4 k-steps (32 VGPR)
    #pragma unroll
    for (int rs = 0; rs < 2; ++rs) {
        const unsigned short* p = zl + (size_t)(R0 + rs * 16 + m) * DDIM + quad * 8;
        #pragma unroll
        for (int kk = 0; kk < 4; ++kk) a[rs][kk] = *(const short8*)(p + kk * 32);
    }
    floatx4 rsum[2];
    rsum[0] = (floatx4){0.f, 0.f, 0.f, 0.f};
    rsum[1] = (floatx4){0.f, 0.f, 0.f, 0.f};

    const unsigned short* bp = zl + (size_t)(C0 + m) * DDIM + quad * 8;
    short8 b0[4], b1[4];
    #pragma unroll
    for (int k = 0; k < 4; ++k) b0[k] = *(const short8*)(bp + k * 32);

    for (int cs = 0; cs < 32; cs += 2) {      // 16-col steps, paired double-buffer
        const unsigned short* q1 = bp + (size_t)(cs + 1) * (16 * DDIM);
        #pragma unroll
        for (int k = 0; k < 4; ++k) b1[k] = *(const short8*)(q1 + k * 32);
        SIMSTEP(b0, cs)
        if (cs + 2 < 32) {
            const unsigned short* q2 = bp + (size_t)(cs + 2) * (16 * DDIM);
            #pragma unroll
            for (int k = 0; k < 4; ++k) b0[k] = *(const short8*)(q2 + k * 32);
        }
        SIMSTEP(b1, cs + 1)
    }

    // reduce across the 16 column-lanes (bits 0..3 of lane)
    #pragma unroll
    for (int off = 1; off < 16; off <<= 1)
        #pragma unroll
        for (int rs = 0; rs < 2; ++rs)
            #pragma unroll
            for (int c = 0; c < 4; ++c)
                rsum[rs][c] += __shfl_xor(rsum[rs][c], off);
    if (m == 0) {                             // plain stores: unique (cg,row) per value
        #pragma unroll
        for (int rs = 0; rs < 2; ++rs)
            #pragma unroll
            for (int c = 0; c < 4; ++c) {
                int rg = R0 + rs * 16 + quad * 4 + c;
                rowpart[cg * 16384 + l4 + rg] = rsum[rs][c];
            }
    }
}

// ---------------- kernel 3: per-row loss from rowpart/diag/pos, 1 atomic per block ---------
__global__ __launch_bounds__(256) void k_loss(const float* __restrict__ jv,
                                              const float* __restrict__ rowpart,
                                              const float* __restrict__ diag,
                                              const float* __restrict__ pos,
                                              float* __restrict__ wsf) {
    __shared__ float sred[256];
    int tid = threadIdx.x;
    int r = blockIdx.x * 256 + tid;           // 64 blocks x 256 = 16384 rows
    int n = r & 4095;
    float tot = 0.f;
    #pragma unroll
    for (int g = 0; g < 8; ++g) tot += rowpart[g * 16384 + r];
    float denom = tot - __builtin_amdgcn_exp2f(diag[r]);   // exact cancel of diagonal term
    float contrib = LN2 * (__builtin_amdgcn_logf(denom) - pos[r]);
    float local = contrib * jv[n & (NHALF - 1)];
    sred[tid] = local; __syncthreads();
    for (int off = 128; off > 0; off >>= 1) {
        if (tid < off) sred[tid] += sred[tid + off];
        __syncthreads();
    }
    if (tid == 0) atomicAdd(&wsf[0], sred[0]);
}

// ---------------- kernel 4: final scalar ---------------------------------------------------
__global__ void k_final(const float* __restrict__ wsf, float* __restrict__ out) {
    if (threadIdx.x == 0) out[0] = wsf[0] / (2.f * wsf[1]);
}

extern "C" void kernel_launch(void* const* d_in, const int* in_sizes, int n_in,
                              void* d_out, int out_size, void* d_ws, size_t ws_size,
                              hipStream_t stream) {
    const float* emb_i = (const float*)d_in[0];
    const float* emb_j = (const float*)d_in[1];
    const float* jv    = (const float*)d_in[2];
    float* wsf     = (float*)d_ws;
    float* rowpart = wsf + WS_ROWPART_OFF;
    float* diag    = wsf + WS_DIAG_OFF;
    float* pos     = wsf + WS_POS_OFF;
    unsigned short* z = (unsigned short*)((char*)d_ws + WS_Z_BYTE_OFF);
    float* out = (float*)d_out;

    k_norm <<<2049, 256, 0, stream>>>(emb_i, emb_j, jv, wsf, z);
    k_sim  <<<1024, 256, 0, stream>>>(z, rowpart, diag, pos);
    k_loss <<<64,   256, 0, stream>>>(jv, rowpart, diag, pos, wsf);
    k_final<<<1,    64,  0, stream>>>(wsf, out);
}